// Round 6
// baseline (1970.482 us; speedup 1.0000x reference)
//
#include <hip/hip_runtime.h>
#include <float.h>

#define NEMB 1024
#define EDIM 256
#define BM   128    // rows per block (z tile); 2 rows per lane
#define HW   4096   // 64*64
#define NT   1024   // 16 waves
#define NW   (NT / 64)
#define NB   32     // codewords per accumulator group (2 groups)
#define ZQ_ELEMS 33554432   // 32*256*4096

// numpy FLOAT_pairwise_sum of squares, n=256: two 128-blocks, 8 accumulators
// r[j] += a[8i+j], tree-combine ((r0+r1)+(r2+r3))+((r4+r5)+(r6+r7)), then
// blk0+blk1. Squares rounded separately (contract off).
template <typename F>
__device__ __forceinline__ float np_sumsq_256(F get) {
#pragma clang fp contract(off)
    float blk[2];
#pragma unroll
    for (int h = 0; h < 2; ++h) {
        const int base = h * 128;
        float r[8];
#pragma unroll
        for (int j = 0; j < 8; ++j) {
            float v = get(base + j);
            r[j] = v * v;
        }
        for (int i = 8; i < 128; i += 8) {
#pragma unroll
            for (int j = 0; j < 8; ++j) {
                float v = get(base + i + j);
                float p = v * v;
                r[j] = r[j] + p;
            }
        }
        blk[h] = ((r[0] + r[1]) + (r[2] + r[3])) + ((r[4] + r[5]) + (r[6] + r[7]));
    }
    return blk[0] + blk[1];
}

__global__ __launch_bounds__(256) void esq_kernel(const float* __restrict__ emb,
                                                  float* __restrict__ esq) {
    int n = blockIdx.x * 256 + threadIdx.x;
    const float* e = emb + (size_t)n * EDIM;
    esq[n] = np_sumsq_256([&](int k) { return e[k]; });
}

// z tile, PAIR-INTERLEAVED over 128 rows: z(k,row) at word
// (k>>1)*256 + 2*row + (k&1). Lane r owns rows r and r+64; each ds_read_b64
// covers dwords {2r,2r+1} over a 128-dword segment -> conflict-free.
//
// ROUND-6 CHANGES (lgkm-drain theory + allocator pinning):
// 1. ds_read (z) and s_load (emb) share lgkmcnt, and SMEM returns OOO, so
//    every ds-consume forces lgkmcnt(0), draining the in-flight emb s_load
//    queue (~200 cy L2 latency exposed). R5 paid that 256x per wave (one
//    per 128-FMA block) ~= the measured 43% no-issue. Now: 2 groups x 32
//    codewords; one 8-k z chunk (8 ds_read_b64, single-buffered) serves a
//    512-FMA pure-SMEM block -> 128 drains/wave, 2x the s_load slack each.
// 2. amdgpu_waves_per_eu(4,4): real occupancy is LDS-bound at 1 block/CU =
//    4 waves/SIMD, but the allocator targeted 8/SIMD (64-VGPR cap) and
//    SPILLED in R2/R5 (WRITE_SIZE +82 MB scratch). Pin 4/4 -> 128-VGPR
//    budget; audited demand ~95-100 (acc 64 + zc 16 + misc).
__global__ __launch_bounds__(NT)
__attribute__((amdgpu_waves_per_eu(4, 4)))
void vq_kernel(const float* __restrict__ z,
               const float* __restrict__ emb,
               const float* __restrict__ esq,
               float* __restrict__ out) {
    __shared__ float zl[BM * EDIM];   // 128 KiB -> 1 block/CU, 16 waves/CU

    const int t   = threadIdx.x;
    const int blk = blockIdx.x;           // 1024 blocks: 32 per batch image
    const int b   = blk >> 5;
    const int hw0 = (blk & 31) * BM;
    const float* zbase = z + (size_t)b * EDIM * HW;

    // ---- stage z tile: 8192 float4, 8 per thread, coalesced along hw ----
#pragma unroll
    for (int pass = 0; pass < 8; ++pass) {
        int f4 = pass * NT + t;
        int r4 = (f4 & 31) * 4;
        int k  = f4 >> 5;
        float4 v = *(const float4*)(zbase + (size_t)k * HW + hw0 + r4);
        int w = (k >> 1) * 256 + 2 * r4 + (k & 1);
        zl[w + 0] = v.x;
        zl[w + 2] = v.y;
        zl[w + 4] = v.z;
        zl[w + 6] = v.w;
    }
    __syncthreads();

    const int r = t & 63;                 // lane id; owns rows r and r+64
    const float* zr = zl + 2 * r;
    // z_sq with exact numpy pairwise semantics (redundant per wave; cheap)
    const float zsq0 = np_sumsq_256([&](int k) { return zr[(k >> 1) * 256 + (k & 1)]; });
    const float zsq1 = np_sumsq_256([&](int k) { return zr[(k >> 1) * 256 + 128 + (k & 1)]; });

    // wave id -> 64-codeword quota (uniform -> scalar emb loads)
    const int q = __builtin_amdgcn_readfirstlane(t >> 6);

    float best0 = FLT_MAX, best1 = FLT_MAX;
    int   bidx0 = 0,       bidx1 = 0;

#pragma unroll 1
    for (int g = 0; g < 2; ++g) {
        const int n0 = q * 64 + g * NB;
        float acc0[NB], acc1[NB];
#pragma unroll
        for (int j = 0; j < NB; ++j) { acc0[j] = 0.f; acc1[j] = 0.f; }

#pragma unroll 1
        for (int kc = 0; kc < EDIM; kc += 8) {
            // 8-k z chunk, both rows: 8 ds_read_b64, then a pure-SMEM
            // 512-FMA block (no ds in flight during emb consumption).
            float2 zc[8];   // [0..3] row r, [4..7] row r+64
            const int m0 = kc >> 1;
#pragma unroll
            for (int u = 0; u < 4; ++u) {
                zc[u]     = *(const float2*)(zr + (m0 + u) * 256);
                zc[4 + u] = *(const float2*)(zr + (m0 + u) * 256 + 128);
            }
            // e_z: strictly sequential fp32 FMA over k per codeword per row
            // (chunk-ascending, pair-ascending, .x before .y) — bit-identical
            // numpy microkernel order. er chunk is 32 B -> s_load_dwordx8.
#pragma unroll
            for (int j = 0; j < NB; ++j) {
                const float* er = emb + (size_t)(n0 + j) * EDIM + kc;
                float a0 = acc0[j], a1 = acc1[j];
#pragma unroll
                for (int u = 0; u < 4; ++u) {
                    a0 = fmaf(zc[u].x, er[2 * u + 0], a0);
                    a0 = fmaf(zc[u].y, er[2 * u + 1], a0);
                }
#pragma unroll
                for (int u = 0; u < 4; ++u) {
                    a1 = fmaf(zc[4 + u].x, er[2 * u + 0], a1);
                    a1 = fmaf(zc[4 + u].y, er[2 * u + 1], a1);
                }
                acc0[j] = a0; acc1[j] = a1;
            }
        }

#pragma unroll
        for (int j = 0; j < NB; ++j) {
            // numpy: dist = RN( RN(zsq+esq) - 2*ez ); 2*ez exact -> fma form
            // is bit-identical.
            float es = esq[n0 + j];
            float t1 = zsq0 + es;
            float d  = fmaf(-2.f, acc0[j], t1);
            if (d < best0) { best0 = d; bidx0 = n0 + j; }   // strict <
            float t2 = zsq1 + es;
            float d2 = fmaf(-2.f, acc1[j], t2);
            if (d2 < best1) { best1 = d2; bidx1 = n0 + j; }
        }
    }

    // ---- cross-wave (min,idx) reduction, reusing zl ----
    __syncthreads();                        // all zl reads done
    float* rv   = zl;                       // [NW*BM] best value
    int*   ri   = (int*)(zl + NW * BM);     // [NW*BM] best idx
    int*   ifin = (int*)(zl + 2 * NW * BM); // [BM]    final idx per row
    rv[q * BM + r]      = best0;
    rv[q * BM + r + 64] = best1;
    ri[q * BM + r]      = bidx0;
    ri[q * BM + r + 64] = bidx1;
    __syncthreads();
    if (t < BM) {
        float bv = rv[t];
        int   bi = ri[t];
#pragma unroll
        for (int w = 1; w < NW; ++w) {
            float v = rv[w * BM + t];
            int   i = ri[w * BM + t];
            // waves cover ascending idx ranges; strict < keeps lowest idx
            if (v < bv) { bv = v; bi = i; }
        }
        ifin[t] = bi;
        out[(size_t)ZQ_ELEMS + (size_t)blk * BM + t] = (float)bi;  // idx as float
    }
    __syncthreads();

    // ---- z_q[b][c][hw] = emb[idx[hw]][c], coalesced float4 along hw ----
    float* zq = out + (size_t)b * EDIM * HW;
#pragma unroll
    for (int pass = 0; pass < 8; ++pass) {
        int f4 = pass * NT + t;
        int r4 = (f4 & 31) * 4;
        int c  = f4 >> 5;
        float4 v;
        v.x = emb[(size_t)ifin[r4 + 0] * EDIM + c];
        v.y = emb[(size_t)ifin[r4 + 1] * EDIM + c];
        v.z = emb[(size_t)ifin[r4 + 2] * EDIM + c];
        v.w = emb[(size_t)ifin[r4 + 3] * EDIM + c];
        *(float4*)(zq + (size_t)c * HW + hw0 + r4) = v;
    }
}

extern "C" void kernel_launch(void* const* d_in, const int* in_sizes, int n_in,
                              void* d_out, int out_size, void* d_ws, size_t ws_size,
                              hipStream_t stream) {
    const float* z   = (const float*)d_in[0];   // [32,256,64,64]
    const float* emb = (const float*)d_in[1];   // [1024,256]
    float* out = (float*)d_out;                 // 33554432 z_q + 131072 idx (as float)
    float* esq = (float*)d_ws;                  // 1024 floats scratch

    esq_kernel<<<NEMB / 256, 256, 0, stream>>>(emb, esq);
    vq_kernel<<<131072 / BM, NT, 0, stream>>>(z, emb, esq, out);
}